// Round 6
// baseline (598.395 us; speedup 1.0000x reference)
//
#include <hip/hip_runtime.h>
#include <hip/hip_bf16.h>
#include <math.h>

#define B_ 4
#define H_ 256
#define W_ 256
#define C_ 128
#define HEADS_ 4
#define HD_ 32
#define WS_ 8
#define SHIFT_ 4
#define T_ 64
#define NW_ 1024
#define M_ (B_*NW_*T_)   /* 262144 tokens */

typedef float floatx4 __attribute__((ext_vector_type(4)));
typedef short bf16x8 __attribute__((ext_vector_type(8)));   // 8 bf16 in 4 VGPRs
typedef unsigned short ushort8v __attribute__((ext_vector_type(8)));

#define MFMA16(a,b,c) __builtin_amdgcn_mfma_f32_16x16x32_bf16(a,b,c,0,0,0)

__device__ __forceinline__ unsigned short f2b(float f){
    union { float f; unsigned int i; } c; c.f = f;
    unsigned int r = c.i + 0x7FFFu + ((c.i >> 16) & 1u);
    return (unsigned short)(r >> 16);
}
__device__ __forceinline__ int region_id(int x){ return (x < 248) ? 0 : ((x < 252) ? 1 : 2); }

__device__ __forceinline__ bf16x8 ldfrag(const unsigned short* p){
    return *(const bf16x8*)p;                       // ds_read_b128 / global_load_dwordx4
}
__device__ __forceinline__ bf16x8 ldfrag_strided(const unsigned short* p, int stride){
    ushort8v u;
    #pragma unroll
    for (int j = 0; j < 8; j++) u[j] = p[j*stride];
    return __builtin_bit_cast(bf16x8, u);
}
__device__ __forceinline__ floatx4 fzero(){ floatx4 v = {0.f,0.f,0.f,0.f}; return v; }

// exact-gelu via A&S 7.1.26 erf (|err|<=1.5e-7); v_rcp instead of full division.
__device__ __forceinline__ float gelu_fast(float x){
    float z = x * 0.70710678118654752f;
    float az = fabsf(z);
    float t = __builtin_amdgcn_rcpf(fmaf(0.3275911f, az, 1.0f));
    float poly = t*(0.254829592f + t*(-0.284496736f + t*(1.421413741f +
                 t*(-1.453152027f + t*1.061405429f))));
    float e = __expf(-z*z);
    float er = 1.0f - poly*e;
    er = (z < 0.f) ? -er : er;
    return 0.5f * x * (1.0f + er);
}

// ---------------- workspace layout (ushort offsets) ----------------
// n-major bf16 weights: Wt[n*K + k] = W[k][n]  (B-fragment = 16B contiguous)
#define WSO_QT   0          /* 128x128 */
#define WSO_KT   16384
#define WSO_VT   32768
#define WSO_PT   49152
#define WSO_W1T  65536      /* [512 n][128 k] */
#define WSO_W2T  131072     /* [128 n][512 k] */
#define WSO_BIAS 196608     /* float[4][64][64] pre-gathered rpb */
#define WS_BYTES_NEEDED (196608u*2u + 16384u*4u)   /* 458752 */

// K0: one-time weight convert/transpose + rel-pos-bias gather.
// COALESCED linear reads; scattered u16 writes (lines fully covered by
// neighboring threads -> write-combine in L2). 256 blocks for latency hiding.
__global__ __launch_bounds__(256) void prep_weights_kernel(
        const float* __restrict__ qw, const float* __restrict__ kw,
        const float* __restrict__ vw, const float* __restrict__ pw,
        const float* __restrict__ fc1, const float* __restrict__ fc2,
        const float* __restrict__ rpb, unsigned short* __restrict__ ws)
{
    int tid = blockIdx.x * 256 + threadIdx.x;
    int nt = gridDim.x * 256;
    for (int i = tid; i < 16384; i += nt) {          // W[k][n] linear read
        int k = i >> 7, n = i & 127;
        int o = n*128 + k;
        ws[WSO_QT + o] = f2b(qw[i]);
        ws[WSO_KT + o] = f2b(kw[i]);
        ws[WSO_VT + o] = f2b(vw[i]);
        ws[WSO_PT + o] = f2b(pw[i]);
    }
    for (int i = tid; i < 65536; i += nt) {          // fc1[k][n], k<128,n<512
        int k = i >> 9, n = i & 511;
        ws[WSO_W1T + n*128 + k] = f2b(fc1[i]);
    }
    for (int i = tid; i < 65536; i += nt) {          // fc2[k][n], k<512,n<128
        int k = i >> 7, n = i & 127;
        ws[WSO_W2T + n*512 + k] = f2b(fc2[i]);
    }
    float* bt = (float*)(ws + WSO_BIAS);
    for (int i = tid; i < 16384; i += nt) {
        int h = i >> 12, q = (i >> 6) & 63, k = i & 63;
        int th = q >> 3, tw = q & 7, jh = k >> 3, jw = k & 7;
        bt[i] = rpb[((th - jh + 7)*15 + (tw - jw + 7))*HEADS_ + h];
    }
}

// C[64x128] = Xs[64x128] @ Wt(n-major global bf16); wave wv owns n-cols [32wv,32wv+32).
__device__ __forceinline__ void gemm64x128_g(
        const unsigned short (*Xs)[136], const unsigned short* __restrict__ Wt,
        int wv, int quad, int l15, floatx4 acc[4][2])
{
    #pragma unroll
    for (int c = 0; c < 4; c++) {
        bf16x8 bf0 = ldfrag(Wt + (size_t)(32*wv + l15)*128      + c*32 + quad*8);
        bf16x8 bf1 = ldfrag(Wt + (size_t)(32*wv + 16 + l15)*128 + c*32 + quad*8);
        #pragma unroll
        for (int m = 0; m < 4; m++) {
            bf16x8 af = ldfrag(&Xs[16*m + l15][c*32 + quad*8]);
            acc[m][0] = MFMA16(af, bf0, acc[m][0]);
            acc[m][1] = MFMA16(af, bf1, acc[m][1]);
        }
    }
}

// Fused whole-layer kernel. LDS = 40960B exactly -> 4 blocks/CU.
// Region map (byte offsets in LDS[40960]):
//   [0,17408)     Xs[64][136]  -> Ph(waves 0-2) -> G[64][72] ; Fb low part
//   [17408,35840) Ks[64][136]  -> VsT[128][72]  -> As[64][136]; Fb high part
//   [35840,40960) Ph(wave 3)   -> RB stats (512B)
// Fb (fp32 staging) = [64][140] skewed (seg*36), spans [0,35840).
__global__ __launch_bounds__(256, 4) void swin_fused_kernel(
        const float* __restrict__ hidden,
        const float* __restrict__ ln1_s, const float* __restrict__ ln1_b,
        const float* __restrict__ q_b, const float* __restrict__ k_b,
        const float* __restrict__ v_b, const float* __restrict__ p_b,
        const float* __restrict__ ln2_s, const float* __restrict__ ln2_b,
        const float* __restrict__ b1, const float* __restrict__ b2,
        const unsigned short* __restrict__ wsu,
        float* __restrict__ outp)
{
    __shared__ __align__(16) unsigned char LDS[40960];
    unsigned short (*Xs)[136] = (unsigned short(*)[136])LDS;
    unsigned short (*Ks)[136] = (unsigned short(*)[136])(LDS + 17408);
    unsigned short (*VsT)[72] = (unsigned short(*)[72])(LDS + 17408);

    int tid = threadIdx.x;
    int wv = tid >> 6, lane = tid & 63;      // wv doubles as head id
    int quad = lane >> 4, l15 = lane & 15;
    int gw = blockIdx.x;
    int wi = gw & (NW_-1), b = gw >> 10;
    int hb = wi >> 5, wb = wi & 31;

    // ================= LN1 (4 lanes/row, shift-gather) -> Xs =================
    {
        int rloc = lane >> 2;                 // 0..15
        int t = wv*16 + rloc;
        int th = t >> 3, tw = t & 7;
        int h = (hb*8 + th + SHIFT_) & 255;
        int w = (wb*8 + tw + SHIFT_) & 255;
        int c0 = (lane & 3) * 32;
        const float* xp = hidden + ((size_t)((b<<16) + (h<<8) + w)) * C_ + c0;
        float4 xv[8];
        float s = 0.f, ss = 0.f;
        #pragma unroll
        for (int i = 0; i < 8; i++) {
            xv[i] = *((const float4*)xp + i);
            s  += xv[i].x + xv[i].y + xv[i].z + xv[i].w;
            ss += xv[i].x*xv[i].x + xv[i].y*xv[i].y + xv[i].z*xv[i].z + xv[i].w*xv[i].w;
        }
        s  += __shfl_xor(s, 1, 64);  s  += __shfl_xor(s, 2, 64);
        ss += __shfl_xor(ss, 1, 64); ss += __shfl_xor(ss, 2, 64);
        float mean = s * (1.0f/C_);
        float var  = ss * (1.0f/C_) - mean*mean;
        float rstd = __builtin_amdgcn_rsqf(var + 1e-5f);
        #pragma unroll
        for (int i = 0; i < 8; i++) {
            float4 sc = *((const float4*)(ln1_s + c0) + i);
            float4 bi = *((const float4*)(ln1_b + c0) + i);
            ushort4 o;
            o.x = f2b((xv[i].x - mean)*rstd*sc.x + bi.x);
            o.y = f2b((xv[i].y - mean)*rstd*sc.y + bi.y);
            o.z = f2b((xv[i].z - mean)*rstd*sc.z + bi.z);
            o.w = f2b((xv[i].w - mean)*rstd*sc.w + bi.w);
            *(ushort4*)&Xs[t][c0 + 4*i] = o;
        }
    }
    __syncthreads();                          // B1: Xs ready

    // ====== fused Q+K+V GEMM: q->regs, k->Ks, v->packed bf16 regs (vpk) ======
    floatx4 qacc[4][2];
    unsigned int vpk[4][2][2];                // V (bias added), 2 bf16 per u32
    {
        floatx4 kacc[4][2], vacc[4][2];
        #pragma unroll
        for (int m = 0; m < 4; m++) {
            qacc[m][0] = fzero(); qacc[m][1] = fzero();
            kacc[m][0] = fzero(); kacc[m][1] = fzero();
            vacc[m][0] = fzero(); vacc[m][1] = fzero();
        }
        const unsigned short* Qt = wsu + WSO_QT;
        const unsigned short* Kt = wsu + WSO_KT;
        const unsigned short* Vt = wsu + WSO_VT;
        #pragma unroll
        for (int c = 0; c < 4; c++) {
            size_t off0 = (size_t)(32*wv + l15)*128      + c*32 + quad*8;
            size_t off1 = (size_t)(32*wv + 16 + l15)*128 + c*32 + quad*8;
            bf16x8 qf0 = ldfrag(Qt + off0), qf1 = ldfrag(Qt + off1);
            bf16x8 kf0 = ldfrag(Kt + off0), kf1 = ldfrag(Kt + off1);
            bf16x8 vf0 = ldfrag(Vt + off0), vf1 = ldfrag(Vt + off1);
            #pragma unroll
            for (int m = 0; m < 4; m++) {
                bf16x8 af = ldfrag(&Xs[16*m + l15][c*32 + quad*8]);
                qacc[m][0] = MFMA16(af, qf0, qacc[m][0]);
                qacc[m][1] = MFMA16(af, qf1, qacc[m][1]);
                kacc[m][0] = MFMA16(af, kf0, kacc[m][0]);
                kacc[m][1] = MFMA16(af, kf1, kacc[m][1]);
                vacc[m][0] = MFMA16(af, vf0, vacc[m][0]);
                vacc[m][1] = MFMA16(af, vf1, vacc[m][1]);
            }
        }
        float kb0 = k_b[32*wv + l15], kb1 = k_b[32*wv + 16 + l15];
        float vb0 = v_b[32*wv + l15], vb1 = v_b[32*wv + 16 + l15];
        #pragma unroll
        for (int m = 0; m < 4; m++) {
            #pragma unroll
            for (int r = 0; r < 4; r++) {
                int q = 16*m + 4*quad + r;
                Ks[q][32*wv + l15]      = f2b(kacc[m][0][r] + kb0);
                Ks[q][32*wv + 16 + l15] = f2b(kacc[m][1][r] + kb1);
            }
            vpk[m][0][0] = (unsigned int)f2b(vacc[m][0][0] + vb0)
                         | ((unsigned int)f2b(vacc[m][0][1] + vb0) << 16);
            vpk[m][0][1] = (unsigned int)f2b(vacc[m][0][2] + vb0)
                         | ((unsigned int)f2b(vacc[m][0][3] + vb0) << 16);
            vpk[m][1][0] = (unsigned int)f2b(vacc[m][1][0] + vb1)
                         | ((unsigned int)f2b(vacc[m][1][1] + vb1) << 16);
            vpk[m][1][1] = (unsigned int)f2b(vacc[m][1][2] + vb1)
                         | ((unsigned int)f2b(vacc[m][1][3] + vb1) << 16);
        }
    }
    __syncthreads();                          // B2: all Xs A-reads done
    {   // Q (scaled) -> Xs own cols (read back only by this wave)
        const float sc = 0.17677669529663687f;
        float qb0 = q_b[32*wv + l15], qb1 = q_b[32*wv + 16 + l15];
        #pragma unroll
        for (int m = 0; m < 4; m++)
            #pragma unroll
            for (int r = 0; r < 4; r++) {
                int q = 16*m + 4*quad + r;
                Xs[q][32*wv + l15]      = f2b((qacc[m][0][r] + qb0) * sc);
                Xs[q][32*wv + 16 + l15] = f2b((qacc[m][1][r] + qb1) * sc);
            }
    }

    // ==== S^T = K Q^T: sacc[m][n][r] = S[q=16m+l15][k=16n+4quad+r] ====
    floatx4 sacc[4][4];
    #pragma unroll
    for (int m = 0; m < 4; m++)
        #pragma unroll
        for (int n = 0; n < 4; n++) sacc[m][n] = fzero();
    {
        bf16x8 qf[4], kf[4];
        #pragma unroll
        for (int m = 0; m < 4; m++) qf[m] = ldfrag(&Xs[16*m + l15][32*wv + quad*8]);
        #pragma unroll
        for (int n = 0; n < 4; n++) kf[n] = ldfrag(&Ks[16*n + l15][32*wv + quad*8]);
        #pragma unroll
        for (int m = 0; m < 4; m++)
            #pragma unroll
            for (int n = 0; n < 4; n++) sacc[m][n] = MFMA16(kf[n], qf[m], sacc[m][n]);
    }
    __syncthreads();                          // B3: Ks + Xs-Q reads done everywhere

    // ---- unpack V -> VsT (over dead Ks); own rows, same-wave r/w; DS hides
    //      under the softmax VALU below ----
    #pragma unroll
    for (int m = 0; m < 4; m++)
        #pragma unroll
        for (int u = 0; u < 2; u++) {
            uint2 p; p.x = vpk[m][u][0]; p.y = vpk[m][u][1];
            *(uint2*)&VsT[32*wv + 16*u + l15][16*m + 4*quad] = p;
        }

    // ==== bias + shift-mask + softmax over k ====
    {
        const float* bt = (const float*)(wsu + WSO_BIAS) + (wv << 12);
        int cidk[4][4];
        #pragma unroll
        for (int n = 0; n < 4; n++)
            #pragma unroll
            for (int r = 0; r < 4; r++) {
                int kt = 16*n + 4*quad + r;
                cidk[n][r] = region_id(hb*8 + (kt >> 3))*3 + region_id(wb*8 + (kt & 7));
            }
        #pragma unroll
        for (int m = 0; m < 4; m++) {
            int q = 16*m + l15;
            int cidq = region_id(hb*8 + (q >> 3))*3 + region_id(wb*8 + (q & 7));
            float v[4][4];
            float mx = -3.0e38f;
            #pragma unroll
            for (int n = 0; n < 4; n++) {
                float4 bv = *(const float4*)(bt + q*64 + 16*n + 4*quad);
                #pragma unroll
                for (int r = 0; r < 4; r++) {
                    float d = sacc[m][n][r] + bv[r];
                    if (cidq != cidk[n][r]) d -= 100.f;
                    v[n][r] = d;
                    mx = fmaxf(mx, d);
                }
            }
            mx = fmaxf(mx, __shfl_xor(mx, 16, 64));
            mx = fmaxf(mx, __shfl_xor(mx, 32, 64));
            float sum = 0.f;
            #pragma unroll
            for (int n = 0; n < 4; n++)
                #pragma unroll
                for (int r = 0; r < 4; r++) { v[n][r] = __expf(v[n][r] - mx); sum += v[n][r]; }
            sum += __shfl_xor(sum, 16, 64);
            sum += __shfl_xor(sum, 32, 64);
            float inv = __builtin_amdgcn_rcpf(sum);
            #pragma unroll
            for (int n = 0; n < 4; n++)
                #pragma unroll
                for (int r = 0; r < 4; r++) sacc[m][n][r] = v[n][r] * inv;
        }
    }

    // ==== PV: P staged in wave-private LDS (3 waves over dead Xs-Q, 1 spare);
    //      V B-frags are contiguous b128 reads of own VsT rows ====
    unsigned short* Ph = (unsigned short*)(LDS + (wv < 3 ? wv*5120 : 35840));
    floatx4 oacc[4][2];
    #pragma unroll
    for (int m = 0; m < 4; m++) { oacc[m][0] = fzero(); oacc[m][1] = fzero(); }
    #pragma unroll
    for (int kb = 0; kb < 2; kb++) {
        #pragma unroll
        for (int m = 0; m < 4; m++)
            #pragma unroll
            for (int n2 = 0; n2 < 2; n2++)
                #pragma unroll
                for (int r = 0; r < 4; r++)
                    Ph[(16*m + l15)*40 + n2*16 + 4*quad + r] = f2b(sacc[m][2*kb + n2][r]);
        bf16x8 bf0 = ldfrag(&VsT[32*wv + l15][kb*32 + quad*8]);
        bf16x8 bf1 = ldfrag(&VsT[32*wv + 16 + l15][kb*32 + quad*8]);
        #pragma unroll
        for (int m = 0; m < 4; m++) {
            bf16x8 af = ldfrag(&Ph[(16*m + l15)*40 + quad*8]);
            oacc[m][0] = MFMA16(af, bf0, oacc[m][0]);
            oacc[m][1] = MFMA16(af, bf1, oacc[m][1]);
        }
    }
    __syncthreads();                          // B4: all P/VsT reads done
    // ---- attn-out -> Xs (own cols) ----
    #pragma unroll
    for (int m = 0; m < 4; m++)
        #pragma unroll
        for (int r = 0; r < 4; r++) {
            int q = 16*m + 4*quad + r;
            Xs[q][32*wv + l15]      = f2b(oacc[m][0][r]);
            Xs[q][32*wv + 16 + l15] = f2b(oacc[m][1][r]);
        }
    __syncthreads();                          // B5: attn-out visible

    // ==== proj GEMM -> pacc; x = hidden + proj + p_b stays in regs ====
    floatx4 pacc[4][2];
    #pragma unroll
    for (int m = 0; m < 4; m++) { pacc[m][0] = fzero(); pacc[m][1] = fzero(); }
    gemm64x128_g(Xs, wsu + WSO_PT, wv, quad, l15, pacc);
    {
        float pb0 = p_b[32*wv + l15], pb1 = p_b[32*wv + 16 + l15];
        #pragma unroll
        for (int m = 0; m < 4; m++)
            #pragma unroll
            for (int r = 0; r < 4; r++) {
                int t = 16*m + 4*quad + r;
                int th = t >> 3, tw = t & 7;
                int h = (hb*8 + th + SHIFT_) & 255;
                int w = (wb*8 + tw + SHIFT_) & 255;
                size_t src = ((size_t)((b<<16) + (h<<8) + w)) * C_;
                pacc[m][0][r] += pb0 + hidden[src + 32*wv + l15];     // L3-hot
                pacc[m][1][r] += pb1 + hidden[src + 32*wv + 16 + l15];
            }
    }
    __syncthreads();                          // B6: proj A-reads done; LDS free

    // ==== x -> Fb fp32 (stride 140, seg-skewed: 4 lanes/row hit 4 banks) ====
    float* Fb = (float*)LDS;                  // [64][140] skewed, 35840B
    #pragma unroll
    for (int m = 0; m < 4; m++)
        #pragma unroll
        for (int r = 0; r < 4; r++) {
            int q = 16*m + 4*quad + r;
            Fb[q*140 + wv*36 + l15]      = pacc[m][0][r];
            Fb[q*140 + wv*36 + 16 + l15] = pacc[m][1][r];
        }
    __syncthreads();                          // B7: Fb complete

    // ==== LN2 stats (fp32, 4 lanes/row) -> RB[64]{mean,rstd} ====
    float* RB = (float*)(LDS + 35840);
    {
        int rloc = lane >> 2, seg = lane & 3;
        int t = wv*16 + rloc;
        const float4* fp = (const float4*)(Fb + t*140 + seg*36);
        float s = 0.f, ss = 0.f;
        #pragma unroll
        for (int i = 0; i < 8; i++) {
            float4 v = fp[i];
            s  += v.x + v.y + v.z + v.w;
            ss += v.x*v.x + v.y*v.y + v.z*v.z + v.w*v.w;
        }
        s  += __shfl_xor(s, 1, 64);  s  += __shfl_xor(s, 2, 64);
        ss += __shfl_xor(ss, 1, 64); ss += __shfl_xor(ss, 2, 64);
        float mean = s * (1.0f/C_);
        float var  = ss * (1.0f/C_) - mean*mean;
        float rstd = __builtin_amdgcn_rsqf(var + 1e-5f);
        if (seg == 0) { float2 mr; mr.x = mean; mr.y = rstd; *(float2*)&RB[2*t] = mr; }
    }
    __syncthreads();                          // B8: stats ready; Fb dead

    // ==== As = LN2(x) in bf16 (from fp32 regs + stats), over dead VsT ====
    unsigned short (*As)[136] = Ks;           // region reuse
    {
        float s0 = ln2_s[32*wv + l15],      s1 = ln2_s[32*wv + 16 + l15];
        float e0 = ln2_b[32*wv + l15],      e1 = ln2_b[32*wv + 16 + l15];
        #pragma unroll
        for (int m = 0; m < 4; m++)
            #pragma unroll
            for (int r = 0; r < 4; r++) {
                int q = 16*m + 4*quad + r;
                float2 mr = *(const float2*)&RB[2*q];     // broadcast read
                As[q][32*wv + l15]      = f2b((pacc[m][0][r] - mr.x)*mr.y*s0 + e0);
                As[q][32*wv + 16 + l15] = f2b((pacc[m][1][r] - mr.x)*mr.y*s1 + e1);
            }
    }
    __syncthreads();                          // B9: As ready

    // ==== MLP chunk loop; G over dead Xs/Fb-low region ====
    unsigned short (*G)[72] = (unsigned short(*)[72])LDS;   // 9216B
    const unsigned short* W1t = wsu + WSO_W1T;
    const unsigned short* W2t = wsu + WSO_W2T;
    floatx4 acc2[4][2];
    #pragma unroll
    for (int m = 0; m < 4; m++) { acc2[m][0] = fzero(); acc2[m][1] = fzero(); }

    for (int ch = 0; ch < 8; ch++) {
        // stage1: wave owns n-cols [16wv,16wv+16) of chunk
        floatx4 a1[4];
        #pragma unroll
        for (int m = 0; m < 4; m++) a1[m] = fzero();
        #pragma unroll
        for (int kc = 0; kc < 4; kc++) {
            bf16x8 bf = ldfrag(W1t + (size_t)(ch*64 + 16*wv + l15)*128 + kc*32 + quad*8);
            #pragma unroll
            for (int m = 0; m < 4; m++) {
                bf16x8 af = ldfrag(&As[16*m + l15][kc*32 + quad*8]);
                a1[m] = MFMA16(af, bf, a1[m]);
            }
        }
        __syncthreads();                      // prev-chunk G readers done
        {   // bias + gelu -> G (own cols)
            int c_rel = 16*wv + l15;
            float bb = b1[ch*64 + c_rel];
            #pragma unroll
            for (int m = 0; m < 4; m++)
                #pragma unroll
                for (int r = 0; r < 4; r++) {
                    float hh = a1[m][r] + bb;
                    G[16*m + 4*quad + r][c_rel] = f2b(gelu_fast(hh));
                }
        }
        __syncthreads();                      // G complete
        // stage2: wave owns n-cols [32wv,32wv+32); acc2 += G @ W2 chunk
        #pragma unroll
        for (int ki = 0; ki < 2; ki++) {
            bf16x8 bf0 = ldfrag(W2t + (size_t)(32*wv + l15)*512      + ch*64 + ki*32 + quad*8);
            bf16x8 bf1 = ldfrag(W2t + (size_t)(32*wv + 16 + l15)*512 + ch*64 + ki*32 + quad*8);
            #pragma unroll
            for (int m = 0; m < 4; m++) {
                bf16x8 af = ldfrag(&G[16*m + l15][ki*32 + quad*8]);
                acc2[m][0] = MFMA16(af, bf0, acc2[m][0]);
                acc2[m][1] = MFMA16(af, bf1, acc2[m][1]);
            }
        }
    }
    __syncthreads();                          // B10: last G reads done; LDS free

    // ==== final = x + y + b2 -> Fb (skewed) -> coalesced shifted store ====
    {
        float bb0 = b2[32*wv + l15], bb1 = b2[32*wv + 16 + l15];
        #pragma unroll
        for (int m = 0; m < 4; m++)
            #pragma unroll
            for (int r = 0; r < 4; r++) {
                int q = 16*m + 4*quad + r;
                Fb[q*140 + wv*36 + l15]      = pacc[m][0][r] + acc2[m][0][r] + bb0;
                Fb[q*140 + wv*36 + 16 + l15] = pacc[m][1][r] + acc2[m][1][r] + bb1;
            }
        __syncthreads();                      // B11: Fb complete
        int t = tid >> 2;                     // token row 0..63
        int seg = tid & 3;                    // 32-float column segment
        int th = t >> 3, tw = t & 7;
        int h = (hb*8 + th + SHIFT_) & 255;
        int w = (wb*8 + tw + SHIFT_) & 255;
        size_t dst = ((size_t)((b<<16) + (h<<8) + w)) * C_ + seg*32;
        float4* op = (float4*)(outp + dst);
        const float4* fp = (const float4*)(Fb + t*140 + seg*36);
        #pragma unroll
        for (int i = 0; i < 8; i++) op[i] = fp[i];
    }
}

/* ===================== fallback path (ws too small) ===================== */

__device__ __forceinline__ void gemm64x128(
        const unsigned short (*Xs)[136], unsigned short (*Wc)[132],
        const float* __restrict__ Wg, int tid, int wv, int quad, int l15,
        floatx4 acc[4][2])
{
    for (int c = 0; c < 4; c++) {
        __syncthreads();
        #pragma unroll
        for (int it = 0; it < 4; it++) {
            int idx = tid + it*256;
            int kk = idx >> 5;
            int n4 = (idx & 31) * 4;
            float4 v = *(const float4*)(Wg + (size_t)(c*32 + kk)*C_ + n4);
            ushort4 o; o.x=f2b(v.x); o.y=f2b(v.y); o.z=f2b(v.z); o.w=f2b(v.w);
            *(ushort4*)&Wc[kk][n4] = o;
        }
        __syncthreads();
        bf16x8 bf0 = ldfrag_strided(&Wc[quad*8][32*wv + l15],      132);
        bf16x8 bf1 = ldfrag_strided(&Wc[quad*8][32*wv + 16 + l15], 132);
        #pragma unroll
        for (int m = 0; m < 4; m++) {
            bf16x8 af = ldfrag(&Xs[16*m + l15][c*32 + quad*8]);
            acc[m][0] = MFMA16(af, bf0, acc[m][0]);
            acc[m][1] = MFMA16(af, bf1, acc[m][1]);
        }
    }
}

__global__ __launch_bounds__(256) void swin_attn_kernel(
        const float* __restrict__ hidden,
        const float* __restrict__ ln1_s, const float* __restrict__ ln1_b,
        const float* __restrict__ q_w, const float* __restrict__ q_b,
        const float* __restrict__ k_w, const float* __restrict__ k_b,
        const float* __restrict__ v_w, const float* __restrict__ v_b,
        const float* __restrict__ p_w, const float* __restrict__ p_b,
        const float* __restrict__ rpb,
        float* __restrict__ xres)
{
    __shared__ unsigned short Xs[T_][136];
    __shared__ unsigned short Ks[T_][136];
    __shared__ unsigned short Vs[T_][134];
    __shared__ __align__(16) unsigned char U[10240];

    unsigned short (*Wc)[132] = (unsigned short(*)[132])U;
    float* rpbf = (float*)U;

    int tid = threadIdx.x;
    int wv = tid >> 6, lane = tid & 63;
    int quad = lane >> 4, l15 = lane & 15;
    int gw = blockIdx.x;
    int wi = gw & (NW_-1), b = gw >> 10;
    int hb = wi >> 5, wb = wi & 31;

    for (int it = 0; it < 16; it++) {
        int t = wv*16 + it;
        int th = t >> 3, tw = t & 7;
        int h = (hb*8 + th + SHIFT_) & 255;
        int w = (wb*8 + tw + SHIFT_) & 255;
        size_t src = ((size_t)((b<<16) + (h<<8) + w)) * C_;
        float2 u = *(const float2*)(hidden + src + 2*lane);
        float x0 = u.x, x1 = u.y;
        float s = x0 + x1, ss = x0*x0 + x1*x1;
        #pragma unroll
        for (int m = 32; m > 0; m >>= 1) {
            s  += __shfl_xor(s,  m, 64);
            ss += __shfl_xor(ss, m, 64);
        }
        float mean = s * (1.0f/C_);
        float var  = ss * (1.0f/C_) - mean*mean;
        float rstd = rsqrtf(var + 1e-5f);
        int c0 = 2*lane;
        ushort2 o;
        o.x = f2b((x0 - mean) * rstd * ln1_s[c0]   + ln1_b[c0]);
        o.y = f2b((x1 - mean) * rstd * ln1_s[c0+1] + ln1_b[c0+1]);
        *(ushort2*)&Xs[t][c0] = o;
    }

    {
        floatx4 acc[4][2];
        #pragma unroll
        for (int m = 0; m < 4; m++) { acc[m][0] = fzero(); acc[m][1] = fzero(); }
        gemm64x128(Xs, Wc, k_w, tid, wv, quad, l15, acc);
        float kb0 = k_b[32*wv + l15], kb1 = k_b[32*wv + 16 + l15];
        #pragma unroll
        for (int m = 0; m < 4; m++)
            #pragma unroll
            for (int r = 0; r < 4; r++) {
                int q = 16*m + 4*quad + r;
                Ks[q][32*wv + l15]      = f2b(acc[m][0][r] + kb0);
                Ks[q][32*wv + 16 + l15] = f2b(acc[m][1][r] + kb1);
            }
    }
    {
        floatx4 acc[4][2];
        #pragma unroll
        for (int m = 0; m < 4; m++) { acc[m][0] = fzero(); acc[m][1] = fzero(); }
        gemm64x128(Xs, Wc, v_w, tid, wv, quad, l15, acc);
        float vb0 = v_b[32*wv + l15], vb1 = v_b[32*wv + 16 + l15];
        #pragma unroll
        for (int m = 0; m < 4; m++)
            #pragma unroll
            for (int r = 0; r < 4; r++) {
                int q = 16*m + 4*quad + r;
                Vs[q][32*wv + l15]      = f2b(acc[m][0][r] + vb0);
                Vs[q][32*wv + 16 + l15] = f2b(acc[m][1][r] + vb1);
            }
    }
    floatx4 qacc[4][2];
    #pragma unroll
    for (int m = 0; m < 4; m++) { qacc[m][0] = fzero(); qacc[m][1] = fzero(); }
    gemm64x128(Xs, Wc, q_w, tid, wv, quad, l15, qacc);
    __syncthreads();
    for (int i = tid; i < 225*HEADS_; i += 256) rpbf[i] = rpb[i];
    {
        const float sc = 0.17677669529663687f;
        float qb0 = q_b[32*wv + l15], qb1 = q_b[32*wv + 16 + l15];
        #pragma unroll
        for (int m = 0; m < 4; m++)
            #pragma unroll
            for (int r = 0; r < 4; r++) {
                int q = 16*m + 4*quad + r;
                Xs[q][32*wv + l15]      = f2b((qacc[m][0][r] + qb0) * sc);
                Xs[q][32*wv + 16 + l15] = f2b((qacc[m][1][r] + qb1) * sc);
            }
    }
    __syncthreads();

    floatx4 sacc[4][4];
    #pragma unroll
    for (int m = 0; m < 4; m++)
        #pragma unroll
        for (int n = 0; n < 4; n++) sacc[m][n] = fzero();
    {
        bf16x8 qf[4], kf[4];
        #pragma unroll
        for (int m = 0; m < 4; m++) qf[m] = ldfrag(&Xs[16*m + l15][32*wv + quad*8]);
        #pragma unroll
        for (int n = 0; n < 4; n++) kf[n] = ldfrag(&Ks[16*n + l15][32*wv + quad*8]);
        #pragma unroll
        for (int m = 0; m < 4; m++)
            #pragma unroll
            for (int n = 0; n < 4; n++) sacc[m][n] = MFMA16(qf[m], kf[n], sacc[m][n]);
    }
    {
        int jh_[4], jw_[4], cidj_[4];
        #pragma unroll
        for (int n = 0; n < 4; n++) {
            int kt = 16*n + l15;
            jh_[n] = kt >> 3; jw_[n] = kt & 7;
            cidj_[n] = region_id(hb*8 + jh_[n])*3 + region_id(wb*8 + jw_[n]);
        }
        #pragma unroll
        for (int m = 0; m < 4; m++)
            #pragma unroll
            for (int r = 0; r < 4; r++) {
                int q = 16*m + 4*quad + r;
                int th = q >> 3, twq = q & 7;
                int cidi = region_id(hb*8 + th)*3 + region_id(wb*8 + twq);
                float v[4];
                #pragma unroll
                for (int n = 0; n < 4; n++) {
                    float d = sacc[m][n][r];
                    d += rpbf[((th - jh_[n] + 7)*15 + (twq - jw_[n] + 7))*HEADS_ + wv];
                    if (cidi != cidj_[n]) d -= 100.f;
                    v[n] = d;
                }
                float mx = fmaxf(fmaxf(v[0],v[1]), fmaxf(v[2],v[3]));
                #pragma unroll
                for (int off = 1; off < 16; off <<= 1) mx = fmaxf(mx, __shfl_xor(mx, off, 64));
                float sum = 0.f;
                #pragma unroll
                for (int n = 0; n < 4; n++) { v[n] = __expf(v[n] - mx); sum += v[n]; }
                #pragma unroll
                for (int off = 1; off < 16; off <<= 1) sum += __shfl_xor(sum, off, 64);
                float inv = 1.0f / sum;
                #pragma unroll
                for (int n = 0; n < 4; n++) sacc[m][n][r] = v[n] * inv;
            }
    }
    __syncthreads();

    unsigned short* Ph = (wv < 2) ? (&Ks[0][0] + wv*2560)
                                  : ((unsigned short*)U + (wv-2)*2560);
    floatx4 oacc[4][2];
    #pragma unroll
    for (int m = 0; m < 4; m++) { oacc[m][0] = fzero(); oacc[m][1] = fzero(); }
    for (int kb = 0; kb < 2; kb++) {
        #pragma unroll
        for (int m = 0; m < 4; m++)
            #pragma unroll
            for (int r = 0; r < 4; r++) {
                int q = 16*m + 4*quad + r;
                Ph[q*40 + l15]      = f2b(sacc[m][2*kb+0][r]);
                Ph[q*40 + 16 + l15] = f2b(sacc[m][2*kb+1][r]);
            }
        __syncthreads();
        bf16x8 bf0 = ldfrag_strided(&Vs[kb*32 + quad*8][32*wv + l15],      134);
        bf16x8 bf1 = ldfrag_strided(&Vs[kb*32 + quad*8][32*wv + 16 + l15], 134);
        #pragma unroll
        for (int m = 0; m < 4; m++) {
            bf16x8 af = ldfrag(&Ph[(16*m + l15)*40 + quad*8]);
            oacc[m][0] = MFMA16(af, bf0, oacc[m][0]);
            oacc[m][1] = MFMA16(af, bf1, oacc[m][1]);
        }
        __syncthreads();
    }
    #pragma unroll
    for (int m = 0; m < 4; m++)
        #pragma unroll
        for (int r = 0; r < 4; r++) {
            int q = 16*m + 4*quad + r;
            Xs[q][32*wv + l15]      = f2b(oacc[m][0][r]);
            Xs[q][32*wv + 16 + l15] = f2b(oacc[m][1][r]);
        }
    {
        floatx4 acc[4][2];
        #pragma unroll
        for (int m = 0; m < 4; m++) { acc[m][0] = fzero(); acc[m][1] = fzero(); }
        gemm64x128(Xs, Wc, p_w, tid, wv, quad, l15, acc);
        float pb0 = p_b[32*wv + l15], pb1 = p_b[32*wv + 16 + l15];
        #pragma unroll
        for (int m = 0; m < 4; m++)
            #pragma unroll
            for (int r = 0; r < 4; r++) {
                int t = 16*m + 4*quad + r;
                int th = t >> 3, tw = t & 7;
                int h = (hb*8 + th + SHIFT_) & 255;
                int w = (wb*8 + tw + SHIFT_) & 255;
                size_t dst = ((size_t)((b<<16) + (h<<8) + w)) * C_;
                int c0 = 32*wv + l15;
                xres[dst + c0]      = hidden[dst + c0]      + acc[m][0][r] + pb0;
                xres[dst + c0 + 16] = hidden[dst + c0 + 16] + acc[m][1][r] + pb1;
            }
    }
}

__global__ __launch_bounds__(256) void mlp_ln_kernel(
        float* __restrict__ xio,
        const float* __restrict__ ln2_s, const float* __restrict__ ln2_b,
        const float* __restrict__ W1, const float* __restrict__ b1,
        const float* __restrict__ W2, const float* __restrict__ b2)
{
    __shared__ unsigned short As[T_][136];
    __shared__ unsigned short G[T_][72];
    __shared__ unsigned short W1c[C_][68];
    __shared__ unsigned short W2c[T_][132];
    int tid = threadIdx.x, wv = tid >> 6, lane = tid & 63;
    int quad = lane >> 4, l15 = lane & 15;
    size_t row0 = (size_t)blockIdx.x * 64;

    for (int it = 0; it < 16; it++) {
        int t = wv*16 + it;
        const float* xp = xio + (row0 + t)*C_;
        float2 u = *(const float2*)(xp + 2*lane);
        float x0 = u.x, x1 = u.y;
        float s = x0 + x1, ss = x0*x0 + x1*x1;
        #pragma unroll
        for (int m = 32; m > 0; m >>= 1) {
            s  += __shfl_xor(s,  m, 64);
            ss += __shfl_xor(ss, m, 64);
        }
        float mean = s * (1.0f/C_);
        float var  = ss * (1.0f/C_) - mean*mean;
        float rstd = rsqrtf(var + 1e-5f);
        int c0 = 2*lane;
        ushort2 o;
        o.x = f2b((x0 - mean) * rstd * ln2_s[c0]   + ln2_b[c0]);
        o.y = f2b((x1 - mean) * rstd * ln2_s[c0+1] + ln2_b[c0+1]);
        *(ushort2*)&As[t][c0] = o;
    }

    floatx4 acc2[4][2];
    #pragma unroll
    for (int m = 0; m < 4; m++) { acc2[m][0] = fzero(); acc2[m][1] = fzero(); }

    for (int ch = 0; ch < 8; ch++) {
        __syncthreads();
        #pragma unroll
        for (int it = 0; it < 8; it++) {
            int idx = tid + it*256;
            int k = idx >> 4, n4 = (idx & 15) * 4;
            float4 v = *(const float4*)(W1 + (size_t)k*512 + ch*64 + n4);
            ushort4 o; o.x=f2b(v.x); o.y=f2b(v.y); o.z=f2b(v.z); o.w=f2b(v.w);
            *(ushort4*)&W1c[k][n4] = o;
        }
        #pragma unroll
        for (int it = 0; it < 8; it++) {
            int idx = tid + it*256;
            int k = idx >> 5, n4 = (idx & 31) * 4;
            float4 v = *(const float4*)(W2 + (size_t)(ch*64 + k)*C_ + n4);
            ushort4 o; o.x=f2b(v.x); o.y=f2b(v.y); o.z=f2b(v.z); o.w=f2b(v.w);
            *(ushort4*)&W2c[k][n4] = o;
        }
        __syncthreads();
        floatx4 a1[4];
        #pragma unroll
        for (int m = 0; m < 4; m++) a1[m] = fzero();
        #pragma unroll
        for (int kc = 0; kc < 4; kc++) {
            bf16x8 bfrag = ldfrag_strided(&W1c[kc*32 + quad*8][16*wv + l15], 68);
            #pragma unroll
            for (int m = 0; m < 4; m++) {
                bf16x8 af = ldfrag(&As[16*m + l15][kc*32 + quad*8]);
                a1[m] = MFMA16(af, bfrag, a1[m]);
            }
        }
        {
            int c_rel = 16*wv + l15;
            float bb = b1[ch*64 + c_rel];
            #pragma unroll
            for (int m = 0; m < 4; m++)
                #pragma unroll
                for (int r = 0; r < 4; r++) {
                    int q = 16*m + 4*quad + r;
                    float hh = a1[m][r] + bb;
                    float g = 0.5f * hh * (1.0f + erff(hh * 0.70710678118654752f));
                    G[q][c_rel] = f2b(g);
                }
        }
        __syncthreads();
        #pragma unroll
        for (int ki = 0; ki < 2; ki++) {
            bf16x8 bf0 = ldfrag_strided(&W2c[ki*32 + quad*8][32*wv + l15],      132);
            bf16x8 bf1 = ldfrag_strided(&W2c[ki*32 + quad*8][32*wv + 16 + l15], 132);
            #pragma unroll
            for (int m = 0; m < 4; m++) {
                bf16x8 af = ldfrag(&G[16*m + l15][ki*32 + quad*8]);
                acc2[m][0] = MFMA16(af, bf0, acc2[m][0]);
                acc2[m][1] = MFMA16(af, bf1, acc2[m][1]);
            }
        }
    }
    {
        float bb0 = b2[32*wv + l15], bb1 = b2[32*wv + 16 + l15];
        #pragma unroll
        for (int m = 0; m < 4; m++)
            #pragma unroll
            for (int r = 0; r < 4; r++) {
                size_t rr = row0 + 16*m + 4*quad + r;
                int c0 = 32*wv + l15;
                xio[rr*C_ + c0]      += acc2[m][0][r] + bb0;
                xio[rr*C_ + c0 + 16] += acc2[m][1][r] + bb1;
            }
    }
}

extern "C" void kernel_launch(void* const* d_in, const int* in_sizes, int n_in,
                              void* d_out, int out_size, void* d_ws, size_t ws_size,
                              hipStream_t stream) {
    (void)in_sizes; (void)n_in; (void)out_size;
    const float* hidden = (const float*)d_in[0];
    const float* ln1_s  = (const float*)d_in[1];
    const float* ln1_b  = (const float*)d_in[2];
    const float* q_w    = (const float*)d_in[3];
    const float* q_b    = (const float*)d_in[4];
    const float* k_w    = (const float*)d_in[5];
    const float* k_b    = (const float*)d_in[6];
    const float* v_w    = (const float*)d_in[7];
    const float* v_b    = (const float*)d_in[8];
    const float* p_w    = (const float*)d_in[9];
    const float* p_b    = (const float*)d_in[10];
    const float* rpb    = (const float*)d_in[11];
    const float* ln2_s  = (const float*)d_in[12];
    const float* ln2_b  = (const float*)d_in[13];
    const float* fc1_w  = (const float*)d_in[14];
    const float* fc1_b  = (const float*)d_in[15];
    const float* fc2_w  = (const float*)d_in[16];
    const float* fc2_b  = (const float*)d_in[17];
    float* outp = (float*)d_out;

    if (d_ws != nullptr && ws_size >= (size_t)WS_BYTES_NEEDED) {
        unsigned short* wsu = (unsigned short*)d_ws;
        prep_weights_kernel<<<256, 256, 0, stream>>>(q_w, k_w, v_w, p_w,
                fc1_w, fc2_w, rpb, wsu);
        swin_fused_kernel<<<B_*NW_, 256, 0, stream>>>(hidden, ln1_s, ln1_b,
                q_b, k_b, v_b, p_b, ln2_s, ln2_b, fc1_b, fc2_b, wsu, outp);
    } else {
        swin_attn_kernel<<<B_*NW_, 256, 0, stream>>>(hidden, ln1_s, ln1_b,
                q_w, q_b, k_w, k_b, v_w, v_b, p_w, p_b, rpb, outp);
        mlp_ln_kernel<<<M_/64, 256, 0, stream>>>(outp, ln2_s, ln2_b,
                fc1_w, fc1_b, fc2_w, fc2_b);
    }
}

// Round 7
// 533.076 us; speedup vs baseline: 1.1225x; 1.1225x over previous
//
#include <hip/hip_runtime.h>
#include <hip/hip_bf16.h>
#include <math.h>

#define B_ 4
#define H_ 256
#define W_ 256
#define C_ 128
#define HEADS_ 4
#define HD_ 32
#define WS_ 8
#define SHIFT_ 4
#define T_ 64
#define NW_ 1024
#define M_ (B_*NW_*T_)   /* 262144 tokens */

typedef float floatx4 __attribute__((ext_vector_type(4)));
typedef short bf16x8 __attribute__((ext_vector_type(8)));   // 8 bf16 in 4 VGPRs
typedef unsigned short ushort8v __attribute__((ext_vector_type(8)));

#define MFMA16(a,b,c) __builtin_amdgcn_mfma_f32_16x16x32_bf16(a,b,c,0,0,0)

__device__ __forceinline__ unsigned short f2b(float f){
    union { float f; unsigned int i; } c; c.f = f;
    unsigned int r = c.i + 0x7FFFu + ((c.i >> 16) & 1u);
    return (unsigned short)(r >> 16);
}
__device__ __forceinline__ int region_id(int x){ return (x < 248) ? 0 : ((x < 252) ? 1 : 2); }

__device__ __forceinline__ bf16x8 ldfrag(const unsigned short* p){
    return *(const bf16x8*)p;                       // ds_read_b128 / global_load_dwordx4
}
__device__ __forceinline__ bf16x8 ldfrag_strided(const unsigned short* p, int stride){
    ushort8v u;
    #pragma unroll
    for (int j = 0; j < 8; j++) u[j] = p[j*stride];
    return __builtin_bit_cast(bf16x8, u);
}
__device__ __forceinline__ floatx4 fzero(){ floatx4 v = {0.f,0.f,0.f,0.f}; return v; }

// exact-gelu via A&S 7.1.26 erf (|err|<=1.5e-7); v_rcp instead of full division.
__device__ __forceinline__ float gelu_fast(float x){
    float z = x * 0.70710678118654752f;
    float az = fabsf(z);
    float t = __builtin_amdgcn_rcpf(fmaf(0.3275911f, az, 1.0f));
    float poly = t*(0.254829592f + t*(-0.284496736f + t*(1.421413741f +
                 t*(-1.453152027f + t*1.061405429f))));
    float e = __expf(-z*z);
    float er = 1.0f - poly*e;
    er = (z < 0.f) ? -er : er;
    return 0.5f * x * (1.0f + er);
}

// ---------------- workspace layout (ushort offsets) ----------------
// n-major bf16 weights: Wt[n*K + k] = W[k][n]  (B-fragment = 16B contiguous)
#define WSO_QT   0          /* 128x128 */
#define WSO_KT   16384
#define WSO_VT   32768
#define WSO_PT   49152
#define WSO_W1T  65536      /* [512 n][128 k] */
#define WSO_W2T  131072     /* [128 n][512 k] */
#define WSO_BIAS 196608     /* float[4][64][64] pre-gathered rpb */
#define WS_BYTES_NEEDED (196608u*2u + 16384u*4u)   /* 458752 */

// K0: one-time weight convert/transpose + rel-pos-bias gather.
// COALESCED linear reads; scattered u16 writes (lines fully covered by
// neighboring threads -> write-combine in L2). 256 blocks for latency hiding.
__global__ __launch_bounds__(256) void prep_weights_kernel(
        const float* __restrict__ qw, const float* __restrict__ kw,
        const float* __restrict__ vw, const float* __restrict__ pw,
        const float* __restrict__ fc1, const float* __restrict__ fc2,
        const float* __restrict__ rpb, unsigned short* __restrict__ ws)
{
    int tid = blockIdx.x * 256 + threadIdx.x;
    int nt = gridDim.x * 256;
    for (int i = tid; i < 16384; i += nt) {          // W[k][n] linear read
        int k = i >> 7, n = i & 127;
        int o = n*128 + k;
        ws[WSO_QT + o] = f2b(qw[i]);
        ws[WSO_KT + o] = f2b(kw[i]);
        ws[WSO_VT + o] = f2b(vw[i]);
        ws[WSO_PT + o] = f2b(pw[i]);
    }
    for (int i = tid; i < 65536; i += nt) {          // fc1[k][n], k<128,n<512
        int k = i >> 9, n = i & 511;
        ws[WSO_W1T + n*128 + k] = f2b(fc1[i]);
    }
    for (int i = tid; i < 65536; i += nt) {          // fc2[k][n], k<512,n<128
        int k = i >> 7, n = i & 127;
        ws[WSO_W2T + n*512 + k] = f2b(fc2[i]);
    }
    float* bt = (float*)(ws + WSO_BIAS);
    for (int i = tid; i < 16384; i += nt) {
        int h = i >> 12, q = (i >> 6) & 63, k = i & 63;
        int th = q >> 3, tw = q & 7, jh = k >> 3, jw = k & 7;
        bt[i] = rpb[((th - jh + 7)*15 + (tw - jw + 7))*HEADS_ + h];
    }
}

// C[64x128] = Xs[64x128] @ Wt(n-major global bf16); wave wv owns n-cols [32wv,32wv+32).
__device__ __forceinline__ void gemm64x128_g(
        const unsigned short (*Xs)[136], const unsigned short* __restrict__ Wt,
        int wv, int quad, int l15, floatx4 acc[4][2])
{
    #pragma unroll
    for (int c = 0; c < 4; c++) {
        bf16x8 bf0 = ldfrag(Wt + (size_t)(32*wv + l15)*128      + c*32 + quad*8);
        bf16x8 bf1 = ldfrag(Wt + (size_t)(32*wv + 16 + l15)*128 + c*32 + quad*8);
        #pragma unroll
        for (int m = 0; m < 4; m++) {
            bf16x8 af = ldfrag(&Xs[16*m + l15][c*32 + quad*8]);
            acc[m][0] = MFMA16(af, bf0, acc[m][0]);
            acc[m][1] = MFMA16(af, bf1, acc[m][1]);
        }
    }
}

// Fused whole-layer kernel. LDS = 40960B (4 blocks/CU by LDS).
// launch_bounds(256,3): VGPR budget 170 -> NO SPILLS (r6's (256,4) forced 64
// arch VGPRs and spilled ~540MB/dispatch to scratch). Actual VGPR ~84-110
// still yields 4 waves/SIMD -> 4 blocks/CU.
// Region map (byte offsets in LDS[40960]):
//   [0,17408)     Xs[64][136]  -> Ph(waves 0-2) -> G[64][72] ; Fb low part
//   [17408,35840) Ks[64][136]  -> VsT[128][72]  -> As[64][136]; Fb high part
//   [35840,40960) Ph(wave 3)   -> RB stats (512B)
// Fb (fp32 staging) = [64][140] skewed (seg*36), spans [0,35840).
__global__ __launch_bounds__(256, 3) void swin_fused_kernel(
        const float* __restrict__ hidden,
        const float* __restrict__ ln1_s, const float* __restrict__ ln1_b,
        const float* __restrict__ q_b, const float* __restrict__ k_b,
        const float* __restrict__ v_b, const float* __restrict__ p_b,
        const float* __restrict__ ln2_s, const float* __restrict__ ln2_b,
        const float* __restrict__ b1, const float* __restrict__ b2,
        const unsigned short* __restrict__ wsu,
        float* __restrict__ outp)
{
    __shared__ __align__(16) unsigned char LDS[40960];
    unsigned short (*Xs)[136] = (unsigned short(*)[136])LDS;
    unsigned short (*Ks)[136] = (unsigned short(*)[136])(LDS + 17408);
    unsigned short (*VsT)[72] = (unsigned short(*)[72])(LDS + 17408);

    int tid = threadIdx.x;
    int wv = tid >> 6, lane = tid & 63;      // wv doubles as head id
    int quad = lane >> 4, l15 = lane & 15;
    int gw = blockIdx.x;
    int wi = gw & (NW_-1), b = gw >> 10;
    int hb = wi >> 5, wb = wi & 31;

    // ================= LN1 (4 lanes/row, shift-gather) -> Xs =================
    {
        int rloc = lane >> 2;                 // 0..15
        int t = wv*16 + rloc;
        int th = t >> 3, tw = t & 7;
        int h = (hb*8 + th + SHIFT_) & 255;
        int w = (wb*8 + tw + SHIFT_) & 255;
        int c0 = (lane & 3) * 32;
        const float* xp = hidden + ((size_t)((b<<16) + (h<<8) + w)) * C_ + c0;
        float4 xv[8];
        float s = 0.f, ss = 0.f;
        #pragma unroll
        for (int i = 0; i < 8; i++) {
            xv[i] = *((const float4*)xp + i);
            s  += xv[i].x + xv[i].y + xv[i].z + xv[i].w;
            ss += xv[i].x*xv[i].x + xv[i].y*xv[i].y + xv[i].z*xv[i].z + xv[i].w*xv[i].w;
        }
        s  += __shfl_xor(s, 1, 64);  s  += __shfl_xor(s, 2, 64);
        ss += __shfl_xor(ss, 1, 64); ss += __shfl_xor(ss, 2, 64);
        float mean = s * (1.0f/C_);
        float var  = ss * (1.0f/C_) - mean*mean;
        float rstd = __builtin_amdgcn_rsqf(var + 1e-5f);
        #pragma unroll
        for (int i = 0; i < 8; i++) {
            float4 sc = *((const float4*)(ln1_s + c0) + i);
            float4 bi = *((const float4*)(ln1_b + c0) + i);
            ushort4 o;
            o.x = f2b((xv[i].x - mean)*rstd*sc.x + bi.x);
            o.y = f2b((xv[i].y - mean)*rstd*sc.y + bi.y);
            o.z = f2b((xv[i].z - mean)*rstd*sc.z + bi.z);
            o.w = f2b((xv[i].w - mean)*rstd*sc.w + bi.w);
            *(ushort4*)&Xs[t][c0 + 4*i] = o;
        }
    }
    __syncthreads();                          // B1: Xs ready

    // ====== fused Q+K+V GEMM: q->regs, k->Ks, v->packed bf16 regs (vpk) ======
    floatx4 qacc[4][2];
    unsigned int vpk[4][2][2];                // V (bias added), 2 bf16 per u32
    {
        floatx4 kacc[4][2], vacc[4][2];
        #pragma unroll
        for (int m = 0; m < 4; m++) {
            qacc[m][0] = fzero(); qacc[m][1] = fzero();
            kacc[m][0] = fzero(); kacc[m][1] = fzero();
            vacc[m][0] = fzero(); vacc[m][1] = fzero();
        }
        const unsigned short* Qt = wsu + WSO_QT;
        const unsigned short* Kt = wsu + WSO_KT;
        const unsigned short* Vt = wsu + WSO_VT;
        #pragma unroll
        for (int c = 0; c < 4; c++) {
            size_t off0 = (size_t)(32*wv + l15)*128      + c*32 + quad*8;
            size_t off1 = (size_t)(32*wv + 16 + l15)*128 + c*32 + quad*8;
            bf16x8 qf0 = ldfrag(Qt + off0), qf1 = ldfrag(Qt + off1);
            bf16x8 kf0 = ldfrag(Kt + off0), kf1 = ldfrag(Kt + off1);
            bf16x8 vf0 = ldfrag(Vt + off0), vf1 = ldfrag(Vt + off1);
            #pragma unroll
            for (int m = 0; m < 4; m++) {
                bf16x8 af = ldfrag(&Xs[16*m + l15][c*32 + quad*8]);
                qacc[m][0] = MFMA16(af, qf0, qacc[m][0]);
                qacc[m][1] = MFMA16(af, qf1, qacc[m][1]);
                kacc[m][0] = MFMA16(af, kf0, kacc[m][0]);
                kacc[m][1] = MFMA16(af, kf1, kacc[m][1]);
                vacc[m][0] = MFMA16(af, vf0, vacc[m][0]);
                vacc[m][1] = MFMA16(af, vf1, vacc[m][1]);
            }
        }
        float kb0 = k_b[32*wv + l15], kb1 = k_b[32*wv + 16 + l15];
        float vb0 = v_b[32*wv + l15], vb1 = v_b[32*wv + 16 + l15];
        #pragma unroll
        for (int m = 0; m < 4; m++) {
            #pragma unroll
            for (int r = 0; r < 4; r++) {
                int q = 16*m + 4*quad + r;
                Ks[q][32*wv + l15]      = f2b(kacc[m][0][r] + kb0);
                Ks[q][32*wv + 16 + l15] = f2b(kacc[m][1][r] + kb1);
            }
            vpk[m][0][0] = (unsigned int)f2b(vacc[m][0][0] + vb0)
                         | ((unsigned int)f2b(vacc[m][0][1] + vb0) << 16);
            vpk[m][0][1] = (unsigned int)f2b(vacc[m][0][2] + vb0)
                         | ((unsigned int)f2b(vacc[m][0][3] + vb0) << 16);
            vpk[m][1][0] = (unsigned int)f2b(vacc[m][1][0] + vb1)
                         | ((unsigned int)f2b(vacc[m][1][1] + vb1) << 16);
            vpk[m][1][1] = (unsigned int)f2b(vacc[m][1][2] + vb1)
                         | ((unsigned int)f2b(vacc[m][1][3] + vb1) << 16);
        }
    }
    __syncthreads();                          // B2: all Xs A-reads done
    {   // Q (scaled) -> Xs own cols (read back only by this wave)
        const float sc = 0.17677669529663687f;
        float qb0 = q_b[32*wv + l15], qb1 = q_b[32*wv + 16 + l15];
        #pragma unroll
        for (int m = 0; m < 4; m++)
            #pragma unroll
            for (int r = 0; r < 4; r++) {
                int q = 16*m + 4*quad + r;
                Xs[q][32*wv + l15]      = f2b((qacc[m][0][r] + qb0) * sc);
                Xs[q][32*wv + 16 + l15] = f2b((qacc[m][1][r] + qb1) * sc);
            }
    }

    // ==== S^T = K Q^T: sacc[m][n][r] = S[q=16m+l15][k=16n+4quad+r] ====
    floatx4 sacc[4][4];
    #pragma unroll
    for (int m = 0; m < 4; m++)
        #pragma unroll
        for (int n = 0; n < 4; n++) sacc[m][n] = fzero();
    {
        bf16x8 qf[4], kf[4];
        #pragma unroll
        for (int m = 0; m < 4; m++) qf[m] = ldfrag(&Xs[16*m + l15][32*wv + quad*8]);
        #pragma unroll
        for (int n = 0; n < 4; n++) kf[n] = ldfrag(&Ks[16*n + l15][32*wv + quad*8]);
        #pragma unroll
        for (int m = 0; m < 4; m++)
            #pragma unroll
            for (int n = 0; n < 4; n++) sacc[m][n] = MFMA16(kf[n], qf[m], sacc[m][n]);
    }
    __syncthreads();                          // B3: Ks + Xs-Q reads done everywhere

    // ---- unpack V -> VsT (over dead Ks); own rows, same-wave r/w; DS hides
    //      under the softmax VALU below ----
    #pragma unroll
    for (int m = 0; m < 4; m++)
        #pragma unroll
        for (int u = 0; u < 2; u++) {
            uint2 p; p.x = vpk[m][u][0]; p.y = vpk[m][u][1];
            *(uint2*)&VsT[32*wv + 16*u + l15][16*m + 4*quad] = p;
        }

    // ==== bias + shift-mask + softmax over k ====
    {
        const float* bt = (const float*)(wsu + WSO_BIAS) + (wv << 12);
        int cidk[4][4];
        #pragma unroll
        for (int n = 0; n < 4; n++)
            #pragma unroll
            for (int r = 0; r < 4; r++) {
                int kt = 16*n + 4*quad + r;
                cidk[n][r] = region_id(hb*8 + (kt >> 3))*3 + region_id(wb*8 + (kt & 7));
            }
        #pragma unroll
        for (int m = 0; m < 4; m++) {
            int q = 16*m + l15;
            int cidq = region_id(hb*8 + (q >> 3))*3 + region_id(wb*8 + (q & 7));
            float v[4][4];
            float mx = -3.0e38f;
            #pragma unroll
            for (int n = 0; n < 4; n++) {
                float4 bv = *(const float4*)(bt + q*64 + 16*n + 4*quad);
                #pragma unroll
                for (int r = 0; r < 4; r++) {
                    float d = sacc[m][n][r] + bv[r];
                    if (cidq != cidk[n][r]) d -= 100.f;
                    v[n][r] = d;
                    mx = fmaxf(mx, d);
                }
            }
            mx = fmaxf(mx, __shfl_xor(mx, 16, 64));
            mx = fmaxf(mx, __shfl_xor(mx, 32, 64));
            float sum = 0.f;
            #pragma unroll
            for (int n = 0; n < 4; n++)
                #pragma unroll
                for (int r = 0; r < 4; r++) { v[n][r] = __expf(v[n][r] - mx); sum += v[n][r]; }
            sum += __shfl_xor(sum, 16, 64);
            sum += __shfl_xor(sum, 32, 64);
            float inv = __builtin_amdgcn_rcpf(sum);
            #pragma unroll
            for (int n = 0; n < 4; n++)
                #pragma unroll
                for (int r = 0; r < 4; r++) sacc[m][n][r] = v[n][r] * inv;
        }
    }

    // ==== PV: P staged in wave-private LDS (3 waves over dead Xs-Q, 1 spare);
    //      packed ushort4 writes (r=0..3 contiguous); V = contiguous VsT b128 ====
    unsigned short* Ph = (unsigned short*)(LDS + (wv < 3 ? wv*5120 : 35840));
    floatx4 oacc[4][2];
    #pragma unroll
    for (int m = 0; m < 4; m++) { oacc[m][0] = fzero(); oacc[m][1] = fzero(); }
    #pragma unroll
    for (int kb = 0; kb < 2; kb++) {
        #pragma unroll
        for (int m = 0; m < 4; m++)
            #pragma unroll
            for (int n2 = 0; n2 < 2; n2++) {
                ushort4 o;
                o.x = f2b(sacc[m][2*kb + n2][0]);
                o.y = f2b(sacc[m][2*kb + n2][1]);
                o.z = f2b(sacc[m][2*kb + n2][2]);
                o.w = f2b(sacc[m][2*kb + n2][3]);
                *(ushort4*)&Ph[(16*m + l15)*40 + n2*16 + 4*quad] = o;
            }
        bf16x8 bf0 = ldfrag(&VsT[32*wv + l15][kb*32 + quad*8]);
        bf16x8 bf1 = ldfrag(&VsT[32*wv + 16 + l15][kb*32 + quad*8]);
        #pragma unroll
        for (int m = 0; m < 4; m++) {
            bf16x8 af = ldfrag(&Ph[(16*m + l15)*40 + quad*8]);
            oacc[m][0] = MFMA16(af, bf0, oacc[m][0]);
            oacc[m][1] = MFMA16(af, bf1, oacc[m][1]);
        }
    }
    __syncthreads();                          // B4: all P/VsT reads done
    // ---- attn-out -> Xs (own cols) ----
    #pragma unroll
    for (int m = 0; m < 4; m++)
        #pragma unroll
        for (int r = 0; r < 4; r++) {
            int q = 16*m + 4*quad + r;
            Xs[q][32*wv + l15]      = f2b(oacc[m][0][r]);
            Xs[q][32*wv + 16 + l15] = f2b(oacc[m][1][r]);
        }
    __syncthreads();                          // B5: attn-out visible

    // ==== proj GEMM -> pacc; x = hidden + proj + p_b stays in regs ====
    floatx4 pacc[4][2];
    #pragma unroll
    for (int m = 0; m < 4; m++) { pacc[m][0] = fzero(); pacc[m][1] = fzero(); }
    gemm64x128_g(Xs, wsu + WSO_PT, wv, quad, l15, pacc);
    {
        float pb0 = p_b[32*wv + l15], pb1 = p_b[32*wv + 16 + l15];
        #pragma unroll
        for (int m = 0; m < 4; m++)
            #pragma unroll
            for (int r = 0; r < 4; r++) {
                int t = 16*m + 4*quad + r;
                int th = t >> 3, tw = t & 7;
                int h = (hb*8 + th + SHIFT_) & 255;
                int w = (wb*8 + tw + SHIFT_) & 255;
                size_t src = ((size_t)((b<<16) + (h<<8) + w)) * C_;
                pacc[m][0][r] += pb0 + hidden[src + 32*wv + l15];     // L3-hot
                pacc[m][1][r] += pb1 + hidden[src + 32*wv + 16 + l15];
            }
    }
    __syncthreads();                          // B6: proj A-reads done; LDS free

    // ==== x -> Fb fp32 (stride 140, seg-skewed: 4 lanes/row hit 4 banks) ====
    float* Fb = (float*)LDS;                  // [64][140] skewed, 35840B
    #pragma unroll
    for (int m = 0; m < 4; m++)
        #pragma unroll
        for (int r = 0; r < 4; r++) {
            int q = 16*m + 4*quad + r;
            Fb[q*140 + wv*36 + l15]      = pacc[m][0][r];
            Fb[q*140 + wv*36 + 16 + l15] = pacc[m][1][r];
        }
    __syncthreads();                          // B7: Fb complete

    // ==== LN2 stats (fp32, 4 lanes/row) -> RB[64]{mean,rstd} ====
    float* RB = (float*)(LDS + 35840);
    {
        int rloc = lane >> 2, seg = lane & 3;
        int t = wv*16 + rloc;
        const float4* fp = (const float4*)(Fb + t*140 + seg*36);
        float s = 0.f, ss = 0.f;
        #pragma unroll
        for (int i = 0; i < 8; i++) {
            float4 v = fp[i];
            s  += v.x + v.y + v.z + v.w;
            ss += v.x*v.x + v.y*v.y + v.z*v.z + v.w*v.w;
        }
        s  += __shfl_xor(s, 1, 64);  s  += __shfl_xor(s, 2, 64);
        ss += __shfl_xor(ss, 1, 64); ss += __shfl_xor(ss, 2, 64);
        float mean = s * (1.0f/C_);
        float var  = ss * (1.0f/C_) - mean*mean;
        float rstd = __builtin_amdgcn_rsqf(var + 1e-5f);
        if (seg == 0) { float2 mr; mr.x = mean; mr.y = rstd; *(float2*)&RB[2*t] = mr; }
    }
    __syncthreads();                          // B8: stats ready; Fb dead

    // ==== As = LN2(x) in bf16 (from fp32 regs + stats), over dead VsT ====
    unsigned short (*As)[136] = Ks;           // region reuse
    {
        float s0 = ln2_s[32*wv + l15],      s1 = ln2_s[32*wv + 16 + l15];
        float e0 = ln2_b[32*wv + l15],      e1 = ln2_b[32*wv + 16 + l15];
        #pragma unroll
        for (int m = 0; m < 4; m++)
            #pragma unroll
            for (int r = 0; r < 4; r++) {
                int q = 16*m + 4*quad + r;
                float2 mr = *(const float2*)&RB[2*q];     // broadcast read
                As[q][32*wv + l15]      = f2b((pacc[m][0][r] - mr.x)*mr.y*s0 + e0);
                As[q][32*wv + 16 + l15] = f2b((pacc[m][1][r] - mr.x)*mr.y*s1 + e1);
            }
    }
    __syncthreads();                          // B9: As ready

    // ==== MLP chunk loop; G over dead Xs/Fb-low region ====
    unsigned short (*G)[72] = (unsigned short(*)[72])LDS;   // 9216B
    const unsigned short* W1t = wsu + WSO_W1T;
    const unsigned short* W2t = wsu + WSO_W2T;
    floatx4 acc2[4][2];
    #pragma unroll
    for (int m = 0; m < 4; m++) { acc2[m][0] = fzero(); acc2[m][1] = fzero(); }

    for (int ch = 0; ch < 8; ch++) {
        // stage1: wave owns n-cols [16wv,16wv+16) of chunk
        floatx4 a1[4];
        #pragma unroll
        for (int m = 0; m < 4; m++) a1[m] = fzero();
        #pragma unroll
        for (int kc = 0; kc < 4; kc++) {
            bf16x8 bf = ldfrag(W1t + (size_t)(ch*64 + 16*wv + l15)*128 + kc*32 + quad*8);
            #pragma unroll
            for (int m = 0; m < 4; m++) {
                bf16x8 af = ldfrag(&As[16*m + l15][kc*32 + quad*8]);
                a1[m] = MFMA16(af, bf, a1[m]);
            }
        }
        __syncthreads();                      // prev-chunk G readers done
        {   // bias + gelu -> G (own cols)
            int c_rel = 16*wv + l15;
            float bb = b1[ch*64 + c_rel];
            #pragma unroll
            for (int m = 0; m < 4; m++)
                #pragma unroll
                for (int r = 0; r < 4; r++) {
                    float hh = a1[m][r] + bb;
                    G[16*m + 4*quad + r][c_rel] = f2b(gelu_fast(hh));
                }
        }
        __syncthreads();                      // G complete
        // stage2: wave owns n-cols [32wv,32wv+32); acc2 += G @ W2 chunk
        #pragma unroll
        for (int ki = 0; ki < 2; ki++) {
            bf16x8 bf0 = ldfrag(W2t + (size_t)(32*wv + l15)*512      + ch*64 + ki*32 + quad*8);
            bf16x8 bf1 = ldfrag(W2t + (size_t)(32*wv + 16 + l15)*512 + ch*64 + ki*32 + quad*8);
            #pragma unroll
            for (int m = 0; m < 4; m++) {
                bf16x8 af = ldfrag(&G[16*m + l15][ki*32 + quad*8]);
                acc2[m][0] = MFMA16(af, bf0, acc2[m][0]);
                acc2[m][1] = MFMA16(af, bf1, acc2[m][1]);
            }
        }
    }
    __syncthreads();                          // B10: last G reads done; LDS free

    // ==== final = x + y + b2 -> Fb (skewed) -> coalesced shifted store ====
    {
        float bb0 = b2[32*wv + l15], bb1 = b2[32*wv + 16 + l15];
        #pragma unroll
        for (int m = 0; m < 4; m++)
            #pragma unroll
            for (int r = 0; r < 4; r++) {
                int q = 16*m + 4*quad + r;
                Fb[q*140 + wv*36 + l15]      = pacc[m][0][r] + acc2[m][0][r] + bb0;
                Fb[q*140 + wv*36 + 16 + l15] = pacc[m][1][r] + acc2[m][1][r] + bb1;
            }
        __syncthreads();                      // B11: Fb complete
        int t = tid >> 2;                     // token row 0..63
        int seg = tid & 3;                    // 32-float column segment
        int th = t >> 3, tw = t & 7;
        int h = (hb*8 + th + SHIFT_) & 255;
        int w = (wb*8 + tw + SHIFT_) & 255;
        size_t dst = ((size_t)((b<<16) + (h<<8) + w)) * C_ + seg*32;
        float4* op = (float4*)(outp + dst);
        const float4* fp = (const float4*)(Fb + t*140 + seg*36);
        #pragma unroll
        for (int i = 0; i < 8; i++) op[i] = fp[i];
    }
}

/* ===================== fallback path (ws too small) ===================== */

__device__ __forceinline__ void gemm64x128(
        const unsigned short (*Xs)[136], unsigned short (*Wc)[132],
        const float* __restrict__ Wg, int tid, int wv, int quad, int l15,
        floatx4 acc[4][2])
{
    for (int c = 0; c < 4; c++) {
        __syncthreads();
        #pragma unroll
        for (int it = 0; it < 4; it++) {
            int idx = tid + it*256;
            int kk = idx >> 5;
            int n4 = (idx & 31) * 4;
            float4 v = *(const float4*)(Wg + (size_t)(c*32 + kk)*C_ + n4);
            ushort4 o; o.x=f2b(v.x); o.y=f2b(v.y); o.z=f2b(v.z); o.w=f2b(v.w);
            *(ushort4*)&Wc[kk][n4] = o;
        }
        __syncthreads();
        bf16x8 bf0 = ldfrag_strided(&Wc[quad*8][32*wv + l15],      132);
        bf16x8 bf1 = ldfrag_strided(&Wc[quad*8][32*wv + 16 + l15], 132);
        #pragma unroll
        for (int m = 0; m < 4; m++) {
            bf16x8 af = ldfrag(&Xs[16*m + l15][c*32 + quad*8]);
            acc[m][0] = MFMA16(af, bf0, acc[m][0]);
            acc[m][1] = MFMA16(af, bf1, acc[m][1]);
        }
    }
}

__global__ __launch_bounds__(256) void swin_attn_kernel(
        const float* __restrict__ hidden,
        const float* __restrict__ ln1_s, const float* __restrict__ ln1_b,
        const float* __restrict__ q_w, const float* __restrict__ q_b,
        const float* __restrict__ k_w, const float* __restrict__ k_b,
        const float* __restrict__ v_w, const float* __restrict__ v_b,
        const float* __restrict__ p_w, const float* __restrict__ p_b,
        const float* __restrict__ rpb,
        float* __restrict__ xres)
{
    __shared__ unsigned short Xs[T_][136];
    __shared__ unsigned short Ks[T_][136];
    __shared__ unsigned short Vs[T_][134];
    __shared__ __align__(16) unsigned char U[10240];

    unsigned short (*Wc)[132] = (unsigned short(*)[132])U;
    float* rpbf = (float*)U;

    int tid = threadIdx.x;
    int wv = tid >> 6, lane = tid & 63;
    int quad = lane >> 4, l15 = lane & 15;
    int gw = blockIdx.x;
    int wi = gw & (NW_-1), b = gw >> 10;
    int hb = wi >> 5, wb = wi & 31;

    for (int it = 0; it < 16; it++) {
        int t = wv*16 + it;
        int th = t >> 3, tw = t & 7;
        int h = (hb*8 + th + SHIFT_) & 255;
        int w = (wb*8 + tw + SHIFT_) & 255;
        size_t src = ((size_t)((b<<16) + (h<<8) + w)) * C_;
        float2 u = *(const float2*)(hidden + src + 2*lane);
        float x0 = u.x, x1 = u.y;
        float s = x0 + x1, ss = x0*x0 + x1*x1;
        #pragma unroll
        for (int m = 32; m > 0; m >>= 1) {
            s  += __shfl_xor(s,  m, 64);
            ss += __shfl_xor(ss, m, 64);
        }
        float mean = s * (1.0f/C_);
        float var  = ss * (1.0f/C_) - mean*mean;
        float rstd = rsqrtf(var + 1e-5f);
        int c0 = 2*lane;
        ushort2 o;
        o.x = f2b((x0 - mean) * rstd * ln1_s[c0]   + ln1_b[c0]);
        o.y = f2b((x1 - mean) * rstd * ln1_s[c0+1] + ln1_b[c0+1]);
        *(ushort2*)&Xs[t][c0] = o;
    }

    {
        floatx4 acc[4][2];
        #pragma unroll
        for (int m = 0; m < 4; m++) { acc[m][0] = fzero(); acc[m][1] = fzero(); }
        gemm64x128(Xs, Wc, k_w, tid, wv, quad, l15, acc);
        float kb0 = k_b[32*wv + l15], kb1 = k_b[32*wv + 16 + l15];
        #pragma unroll
        for (int m = 0; m < 4; m++)
            #pragma unroll
            for (int r = 0; r < 4; r++) {
                int q = 16*m + 4*quad + r;
                Ks[q][32*wv + l15]      = f2b(acc[m][0][r] + kb0);
                Ks[q][32*wv + 16 + l15] = f2b(acc[m][1][r] + kb1);
            }
    }
    {
        floatx4 acc[4][2];
        #pragma unroll
        for (int m = 0; m < 4; m++) { acc[m][0] = fzero(); acc[m][1] = fzero(); }
        gemm64x128(Xs, Wc, v_w, tid, wv, quad, l15, acc);
        float vb0 = v_b[32*wv + l15], vb1 = v_b[32*wv + 16 + l15];
        #pragma unroll
        for (int m = 0; m < 4; m++)
            #pragma unroll
            for (int r = 0; r < 4; r++) {
                int q = 16*m + 4*quad + r;
                Vs[q][32*wv + l15]      = f2b(acc[m][0][r] + vb0);
                Vs[q][32*wv + 16 + l15] = f2b(acc[m][1][r] + vb1);
            }
    }
    floatx4 qacc[4][2];
    #pragma unroll
    for (int m = 0; m < 4; m++) { qacc[m][0] = fzero(); qacc[m][1] = fzero(); }
    gemm64x128(Xs, Wc, q_w, tid, wv, quad, l15, qacc);
    __syncthreads();
    for (int i = tid; i < 225*HEADS_; i += 256) rpbf[i] = rpb[i];
    {
        const float sc = 0.17677669529663687f;
        float qb0 = q_b[32*wv + l15], qb1 = q_b[32*wv + 16 + l15];
        #pragma unroll
        for (int m = 0; m < 4; m++)
            #pragma unroll
            for (int r = 0; r < 4; r++) {
                int q = 16*m + 4*quad + r;
                Xs[q][32*wv + l15]      = f2b((qacc[m][0][r] + qb0) * sc);
                Xs[q][32*wv + 16 + l15] = f2b((qacc[m][1][r] + qb1) * sc);
            }
    }
    __syncthreads();

    floatx4 sacc[4][4];
    #pragma unroll
    for (int m = 0; m < 4; m++)
        #pragma unroll
        for (int n = 0; n < 4; n++) sacc[m][n] = fzero();
    {
        bf16x8 qf[4], kf[4];
        #pragma unroll
        for (int m = 0; m < 4; m++) qf[m] = ldfrag(&Xs[16*m + l15][32*wv + quad*8]);
        #pragma unroll
        for (int n = 0; n < 4; n++) kf[n] = ldfrag(&Ks[16*n + l15][32*wv + quad*8]);
        #pragma unroll
        for (int m = 0; m < 4; m++)
            #pragma unroll
            for (int n = 0; n < 4; n++) sacc[m][n] = MFMA16(qf[m], kf[n], sacc[m][n]);
    }
    {
        int jh_[4], jw_[4], cidj_[4];
        #pragma unroll
        for (int n = 0; n < 4; n++) {
            int kt = 16*n + l15;
            jh_[n] = kt >> 3; jw_[n] = kt & 7;
            cidj_[n] = region_id(hb*8 + jh_[n])*3 + region_id(wb*8 + jw_[n]);
        }
        #pragma unroll
        for (int m = 0; m < 4; m++)
            #pragma unroll
            for (int r = 0; r < 4; r++) {
                int q = 16*m + 4*quad + r;
                int th = q >> 3, twq = q & 7;
                int cidi = region_id(hb*8 + th)*3 + region_id(wb*8 + twq);
                float v[4];
                #pragma unroll
                for (int n = 0; n < 4; n++) {
                    float d = sacc[m][n][r];
                    d += rpbf[((th - jh_[n] + 7)*15 + (twq - jw_[n] + 7))*HEADS_ + wv];
                    if (cidi != cidj_[n]) d -= 100.f;
                    v[n] = d;
                }
                float mx = fmaxf(fmaxf(v[0],v[1]), fmaxf(v[2],v[3]));
                #pragma unroll
                for (int off = 1; off < 16; off <<= 1) mx = fmaxf(mx, __shfl_xor(mx, off, 64));
                float sum = 0.f;
                #pragma unroll
                for (int n = 0; n < 4; n++) { v[n] = __expf(v[n] - mx); sum += v[n]; }
                #pragma unroll
                for (int off = 1; off < 16; off <<= 1) sum += __shfl_xor(sum, off, 64);
                float inv = 1.0f / sum;
                #pragma unroll
                for (int n = 0; n < 4; n++) sacc[m][n][r] = v[n] * inv;
            }
    }
    __syncthreads();

    unsigned short* Ph = (wv < 2) ? (&Ks[0][0] + wv*2560)
                                  : ((unsigned short*)U + (wv-2)*2560);
    floatx4 oacc[4][2];
    #pragma unroll
    for (int m = 0; m < 4; m++) { oacc[m][0] = fzero(); oacc[m][1] = fzero(); }
    for (int kb = 0; kb < 2; kb++) {
        #pragma unroll
        for (int m = 0; m < 4; m++)
            #pragma unroll
            for (int r = 0; r < 4; r++) {
                int q = 16*m + 4*quad + r;
                Ph[q*40 + l15]      = f2b(sacc[m][2*kb+0][r]);
                Ph[q*40 + 16 + l15] = f2b(sacc[m][2*kb+1][r]);
            }
        __syncthreads();
        bf16x8 bf0 = ldfrag_strided(&Vs[kb*32 + quad*8][32*wv + l15],      134);
        bf16x8 bf1 = ldfrag_strided(&Vs[kb*32 + quad*8][32*wv + 16 + l15], 134);
        #pragma unroll
        for (int m = 0; m < 4; m++) {
            bf16x8 af = ldfrag(&Ph[(16*m + l15)*40 + quad*8]);
            oacc[m][0] = MFMA16(af, bf0, oacc[m][0]);
            oacc[m][1] = MFMA16(af, bf1, oacc[m][1]);
        }
        __syncthreads();
    }
    #pragma unroll
    for (int m = 0; m < 4; m++)
        #pragma unroll
        for (int r = 0; r < 4; r++) {
            int q = 16*m + 4*quad + r;
            Xs[q][32*wv + l15]      = f2b(oacc[m][0][r]);
            Xs[q][32*wv + 16 + l15] = f2b(oacc[m][1][r]);
        }
    {
        floatx4 acc[4][2];
        #pragma unroll
        for (int m = 0; m < 4; m++) { acc[m][0] = fzero(); acc[m][1] = fzero(); }
        gemm64x128(Xs, Wc, p_w, tid, wv, quad, l15, acc);
        float pb0 = p_b[32*wv + l15], pb1 = p_b[32*wv + 16 + l15];
        #pragma unroll
        for (int m = 0; m < 4; m++)
            #pragma unroll
            for (int r = 0; r < 4; r++) {
                int t = 16*m + 4*quad + r;
                int th = t >> 3, tw = t & 7;
                int h = (hb*8 + th + SHIFT_) & 255;
                int w = (wb*8 + tw + SHIFT_) & 255;
                size_t dst = ((size_t)((b<<16) + (h<<8) + w)) * C_;
                int c0 = 32*wv + l15;
                xres[dst + c0]      = hidden[dst + c0]      + acc[m][0][r] + pb0;
                xres[dst + c0 + 16] = hidden[dst + c0 + 16] + acc[m][1][r] + pb1;
            }
    }
}

__global__ __launch_bounds__(256) void mlp_ln_kernel(
        float* __restrict__ xio,
        const float* __restrict__ ln2_s, const float* __restrict__ ln2_b,
        const float* __restrict__ W1, const float* __restrict__ b1,
        const float* __restrict__ W2, const float* __restrict__ b2)
{
    __shared__ unsigned short As[T_][136];
    __shared__ unsigned short G[T_][72];
    __shared__ unsigned short W1c[C_][68];
    __shared__ unsigned short W2c[T_][132];
    int tid = threadIdx.x, wv = tid >> 6, lane = tid & 63;
    int quad = lane >> 4, l15 = lane & 15;
    size_t row0 = (size_t)blockIdx.x * 64;

    for (int it = 0; it < 16; it++) {
        int t = wv*16 + it;
        const float* xp = xio + (row0 + t)*C_;
        float2 u = *(const float2*)(xp + 2*lane);
        float x0 = u.x, x1 = u.y;
        float s = x0 + x1, ss = x0*x0 + x1*x1;
        #pragma unroll
        for (int m = 32; m > 0; m >>= 1) {
            s  += __shfl_xor(s,  m, 64);
            ss += __shfl_xor(ss, m, 64);
        }
        float mean = s * (1.0f/C_);
        float var  = ss * (1.0f/C_) - mean*mean;
        float rstd = rsqrtf(var + 1e-5f);
        int c0 = 2*lane;
        ushort2 o;
        o.x = f2b((x0 - mean) * rstd * ln2_s[c0]   + ln2_b[c0]);
        o.y = f2b((x1 - mean) * rstd * ln2_s[c0+1] + ln2_b[c0+1]);
        *(ushort2*)&As[t][c0] = o;
    }

    floatx4 acc2[4][2];
    #pragma unroll
    for (int m = 0; m < 4; m++) { acc2[m][0] = fzero(); acc2[m][1] = fzero(); }

    for (int ch = 0; ch < 8; ch++) {
        __syncthreads();
        #pragma unroll
        for (int it = 0; it < 8; it++) {
            int idx = tid + it*256;
            int k = idx >> 4, n4 = (idx & 15) * 4;
            float4 v = *(const float4*)(W1 + (size_t)k*512 + ch*64 + n4);
            ushort4 o; o.x=f2b(v.x); o.y=f2b(v.y); o.z=f2b(v.z); o.w=f2b(v.w);
            *(ushort4*)&W1c[k][n4] = o;
        }
        #pragma unroll
        for (int it = 0; it < 8; it++) {
            int idx = tid + it*256;
            int k = idx >> 5, n4 = (idx & 31) * 4;
            float4 v = *(const float4*)(W2 + (size_t)(ch*64 + k)*C_ + n4);
            ushort4 o; o.x=f2b(v.x); o.y=f2b(v.y); o.z=f2b(v.z); o.w=f2b(v.w);
            *(ushort4*)&W2c[k][n4] = o;
        }
        __syncthreads();
        floatx4 a1[4];
        #pragma unroll
        for (int m = 0; m < 4; m++) a1[m] = fzero();
        #pragma unroll
        for (int kc = 0; kc < 4; kc++) {
            bf16x8 bfrag = ldfrag_strided(&W1c[kc*32 + quad*8][16*wv + l15], 68);
            #pragma unroll
            for (int m = 0; m < 4; m++) {
                bf16x8 af = ldfrag(&As[16*m + l15][kc*32 + quad*8]);
                a1[m] = MFMA16(af, bfrag, a1[m]);
            }
        }
        {
            int c_rel = 16*wv + l15;
            float bb = b1[ch*64 + c_rel];
            #pragma unroll
            for (int m = 0; m < 4; m++)
                #pragma unroll
                for (int r = 0; r < 4; r++) {
                    int q = 16*m + 4*quad + r;
                    float hh = a1[m][r] + bb;
                    float g = 0.5f * hh * (1.0f + erff(hh * 0.70710678118654752f));
                    G[q][c_rel] = f2b(g);
                }
        }
        __syncthreads();
        #pragma unroll
        for (int ki = 0; ki < 2; ki++) {
            bf16x8 bf0 = ldfrag_strided(&W2c[ki*32 + quad*8][32*wv + l15],      132);
            bf16x8 bf1 = ldfrag_strided(&W2c[ki*32 + quad*8][32*wv + 16 + l15], 132);
            #pragma unroll
            for (int m = 0; m < 4; m++) {
                bf16x8 af = ldfrag(&G[16*m + l15][ki*32 + quad*8]);
                acc2[m][0] = MFMA16(af, bf0, acc2[m][0]);
                acc2[m][1] = MFMA16(af, bf1, acc2[m][1]);
            }
        }
    }
    {
        float bb0 = b2[32*wv + l15], bb1 = b2[32*wv + 16 + l15];
        #pragma unroll
        for (int m = 0; m < 4; m++)
            #pragma unroll
            for (int r = 0; r < 4; r++) {
                size_t rr = row0 + 16*m + 4*quad + r;
                int c0 = 32*wv + l15;
                xio[rr*C_ + c0]      += acc2[m][0][r] + bb0;
                xio[rr*C_ + c0 + 16] += acc2[m][1][r] + bb1;
            }
    }
}

extern "C" void kernel_launch(void* const* d_in, const int* in_sizes, int n_in,
                              void* d_out, int out_size, void* d_ws, size_t ws_size,
                              hipStream_t stream) {
    (void)in_sizes; (void)n_in; (void)out_size;
    const float* hidden = (const float*)d_in[0];
    const float* ln1_s  = (const float*)d_in[1];
    const float* ln1_b  = (const float*)d_in[2];
    const float* q_w    = (const float*)d_in[3];
    const float* q_b    = (const float*)d_in[4];
    const float* k_w    = (const float*)d_in[5];
    const float* k_b    = (const float*)d_in[6];
    const float* v_w    = (const float*)d_in[7];
    const float* v_b    = (const float*)d_in[8];
    const float* p_w    = (const float*)d_in[9];
    const float* p_b    = (const float*)d_in[10];
    const float* rpb    = (const float*)d_in[11];
    const float* ln2_s  = (const float*)d_in[12];
    const float* ln2_b  = (const float*)d_in[13];
    const float* fc1_w  = (const float*)d_in[14];
    const float* fc1_b  = (const float*)d_in[15];
    const float* fc2_w  = (const float*)d_in[16];
    const float* fc2_b  = (const float*)d_in[17];
    float* outp = (float*)d_out;

    if (d_ws != nullptr && ws_size >= (size_t)WS_BYTES_NEEDED) {
        unsigned short* wsu = (unsigned short*)d_ws;
        prep_weights_kernel<<<256, 256, 0, stream>>>(q_w, k_w, v_w, p_w,
                fc1_w, fc2_w, rpb, wsu);
        swin_fused_kernel<<<B_*NW_, 256, 0, stream>>>(hidden, ln1_s, ln1_b,
                q_b, k_b, v_b, p_b, ln2_s, ln2_b, fc1_b, fc2_b, wsu, outp);
    } else {
        swin_attn_kernel<<<B_*NW_, 256, 0, stream>>>(hidden, ln1_s, ln1_b,
                q_w, q_b, k_w, k_b, v_w, v_b, p_w, p_b, rpb, outp);
        mlp_ln_kernel<<<M_/64, 256, 0, stream>>>(outp, ln2_s, ln2_b,
                fc1_w, fc1_b, fc2_w, fc2_b);
    }
}